// Round 1
// baseline (330.949 us; speedup 1.0000x reference)
//
#include <hip/hip_runtime.h>
#include <math.h>

// Problem constants
#define NS    8000      // N samples
#define TT    64        // T
#define FF    64        // F
#define EE    8         // E
#define WIN   40        // WINDOW
#define TR    59        // rows of xe kept: t = 5..63
#define NBINS 1024

// ws layout (floats):
//   xeT  [8][59][8000]  = 3,776,000
//   rankT[8][40][8000]  = 2,560,000
//   uT   [40][5][8000]  = 1,600,000
#define XET_SZ  (8*59*8000)
#define RNK_SZ  (8*40*8000)

// ---------------------------------------------------------------------------
// K0: transpose x[:, 5:64, 0:8] -> xeT[e][r][n]  (r = t-5)
// ---------------------------------------------------------------------------
__global__ __launch_bounds__(256) void k_transpose(const float* __restrict__ x,
                                                   float* __restrict__ xeT) {
    int n = blockIdx.x * 256 + threadIdx.x;
    int r = blockIdx.y;              // 0..58
    if (n >= NS) return;
    const float* row = x + (size_t)n * (TT * FF) + (5 + r) * FF;
    float4 a = *(const float4*)(row);
    float4 b = *(const float4*)(row + 4);
    xeT[(0 * TR + r) * NS + n] = a.x;
    xeT[(1 * TR + r) * NS + n] = a.y;
    xeT[(2 * TR + r) * NS + n] = a.z;
    xeT[(3 * TR + r) * NS + n] = a.w;
    xeT[(4 * TR + r) * NS + n] = b.x;
    xeT[(5 * TR + r) * NS + n] = b.y;
    xeT[(6 * TR + r) * NS + n] = b.z;
    xeT[(7 * TR + r) * NS + n] = b.w;
}

// ---------------------------------------------------------------------------
// KR: exact cross-batch descending rank (stable ties by index) per column.
// One block per (w,e). Bucketed counting: monotone bin over [-4,4], histogram,
// suffix offsets (count of strictly-greater buckets), scatter, exact
// within-bucket comparison. Matches jnp stable argsort(-last) semantics.
// ---------------------------------------------------------------------------
__device__ __forceinline__ int binOf(float v) {
    int b = (int)((v + 4.0f) * 128.0f);   // monotone; trunc ok (clamped)
    b = b < 0 ? 0 : b;
    return b > (NBINS - 1) ? (NBINS - 1) : b;
}

__global__ __launch_bounds__(256) void k_rank(const float* __restrict__ xeT,
                                              float* __restrict__ rankT) {
    const int w = blockIdx.x;   // 0..39
    const int e = blockIdx.y;   // 0..7
    __shared__ unsigned hist[NBINS];     // later reused as scatter cursor
    __shared__ unsigned basev[NBINS];    // # elements in strictly greater buckets
    __shared__ unsigned bendv[NBINS];    // basev + bucket count
    __shared__ float          sk[NS];    // scattered values (bucket-grouped)
    __shared__ unsigned short si[NS];    // scattered original indices
    __shared__ unsigned wsum[4];

    const int tid  = threadIdx.x;
    const int lane = tid & 63;
    const int wid  = tid >> 6;
    const float* col = xeT + ((size_t)e * TR + (19 + w)) * NS;   // t = 24+w

    float val[32];
#pragma unroll
    for (int i = 0; i < 32; i++) {
        int idx = tid + i * 256;
        val[i] = (idx < NS) ? col[idx] : 0.0f;
    }
    for (int b = tid; b < NBINS; b += 256) hist[b] = 0;
    __syncthreads();

#pragma unroll
    for (int i = 0; i < 32; i++) {
        int idx = tid + i * 256;
        if (idx < NS) atomicAdd(&hist[binOf(val[i])], 1u);
    }
    __syncthreads();

    // suffix offsets via ascending inclusive scan: base[b] = 8000 - incl_asc[b]
    unsigned h0 = hist[4 * tid + 0];
    unsigned h1 = hist[4 * tid + 1];
    unsigned h2 = hist[4 * tid + 2];
    unsigned h3 = hist[4 * tid + 3];
    unsigned cs = h0 + h1 + h2 + h3;
    unsigned sc = cs;
#pragma unroll
    for (int d = 1; d < 64; d <<= 1) {
        unsigned t2 = __shfl_up(sc, d);
        if (lane >= d) sc += t2;
    }
    if (lane == 63) wsum[wid] = sc;
    __syncthreads();
    unsigned woff = 0;
    for (int i = 0; i < wid; i++) woff += wsum[i];
    unsigned before = woff + (sc - cs);   // exclusive ascending prefix of bin 4*tid

    {
        int b = 4 * tid;
        bendv[b] = NS - before; before += h0; basev[b] = NS - before;
        hist[b] = basev[b];  b++;
        bendv[b] = NS - before; before += h1; basev[b] = NS - before;
        hist[b] = basev[b];  b++;
        bendv[b] = NS - before; before += h2; basev[b] = NS - before;
        hist[b] = basev[b];  b++;
        bendv[b] = NS - before; before += h3; basev[b] = NS - before;
        hist[b] = basev[b];
    }
    __syncthreads();

    // scatter into bucket-grouped order (order within bucket irrelevant)
#pragma unroll
    for (int i = 0; i < 32; i++) {
        int idx = tid + i * 256;
        if (idx < NS) {
            int b = binOf(val[i]);
            unsigned p = atomicAdd(&hist[b], 1u);
            sk[p] = val[i];
            si[p] = (unsigned short)idx;
        }
    }
    __syncthreads();

    // exact rank: greater buckets + within-bucket (value desc, index asc)
    float* outp = rankT + ((size_t)e * WIN + w) * NS;
#pragma unroll 1
    for (int i = 0; i < 32; i++) {
        int p = tid + i * 256;
        if (p < NS) {
            float v = sk[p];
            unsigned idm = si[p];
            int b = binOf(v);
            unsigned lo = basev[b], hi = bendv[b];
            unsigned c = 0;
            for (unsigned q = lo; q < hi; q++) {
                float u2 = sk[q];
                c += (u2 > v) || (u2 == v && si[q] < idm);
            }
            outp[idm] = (float)(basev[b] + c) / 8000.0f;
        }
    }
}

// ---------------------------------------------------------------------------
// KS: per (n, w): window stats (week=5, month=20) + rank read, folded
// immediately into conv channel-127 partials u[k] = sum_c xc[n,w,c]*w127[c,k].
// Also folds the 64 raw channels from x directly.
// ---------------------------------------------------------------------------
__global__ __launch_bounds__(64) void k_stats(const float* __restrict__ x,
                                              const float* __restrict__ cw,
                                              const float* __restrict__ xeT,
                                              const float* __restrict__ rankT,
                                              float* __restrict__ uT) {
    const int n = blockIdx.x * 64 + threadIdx.x;   // 125*64 = 8000 exact
    const int w = blockIdx.y;                      // 0..39  (= t' position)
    const float* W = cw + 127 * 144 * 5;           // only out-channel 127 used

    float ua[5] = {0.f, 0.f, 0.f, 0.f, 0.f};

    // raw channels 0..63: x[n, 24+w, f]
    {
        const float* row = x + (size_t)n * (TT * FF) + (24 + w) * FF;
#pragma unroll
        for (int f = 0; f < FF; f += 4) {
            float4 a = *(const float4*)(row + f);
            float vv0 = a.x, vv1 = a.y, vv2 = a.z, vv3 = a.w;
#pragma unroll
            for (int k = 0; k < 5; k++) {
                ua[k] += vv0 * W[(f + 0) * 5 + k] + vv1 * W[(f + 1) * 5 + k]
                       + vv2 * W[(f + 2) * 5 + k] + vv3 * W[(f + 3) * 5 + k];
            }
        }
    }

    // derived channels: week block at 64..103, month block at 104..143
    for (int e = 0; e < 8; e++) {
        const float* colbase = xeT + (size_t)e * TR * NS + n;
        float xv[20];
#pragma unroll
        for (int i = 0; i < 20; i++) xv[i] = colbase[(size_t)(w + i) * NS];

        float s20 = 0.f, mn20 = xv[0], mx20 = xv[0];
#pragma unroll
        for (int i = 0; i < 20; i++) {
            s20 += xv[i];
            mn20 = fminf(mn20, xv[i]);
            mx20 = fmaxf(mx20, xv[i]);
        }
        float m20 = s20 * (1.0f / 20.0f);
        float d20 = 0.f;
#pragma unroll
        for (int i = 0; i < 20; i++) { float t = xv[i] - m20; d20 += t * t; }
        float sd20 = sqrtf(d20 * (1.0f / 19.0f));

        float s5 = 0.f, mn5 = xv[15], mx5 = xv[15];
#pragma unroll
        for (int i = 15; i < 20; i++) {
            s5 += xv[i];
            mn5 = fminf(mn5, xv[i]);
            mx5 = fmaxf(mx5, xv[i]);
        }
        float m5 = s5 * 0.2f;
        float d5 = 0.f;
#pragma unroll
        for (int i = 15; i < 20; i++) { float t = xv[i] - m5; d5 += t * t; }
        float sd5 = sqrtf(d5 * 0.25f);

        float rk = rankT[((size_t)e * WIN + w) * NS + n];

#pragma unroll
        for (int k = 0; k < 5; k++) {
            float uk;
            uk  = m5   * W[(64  + e) * 5 + k];
            uk += sd5  * W[(72  + e) * 5 + k];
            uk += rk   * (W[(80 + e) * 5 + k] + W[(120 + e) * 5 + k]);
            uk += mx5  * W[(88  + e) * 5 + k];
            uk += mn5  * W[(96  + e) * 5 + k];
            uk += m20  * W[(104 + e) * 5 + k];
            uk += sd20 * W[(112 + e) * 5 + k];
            uk += mx20 * W[(128 + e) * 5 + k];
            uk += mn20 * W[(136 + e) * 5 + k];
            ua[k] += uk;
        }
    }

    // uT[w][k][n]
    float* o = uT + (size_t)(w * 5) * NS + n;
    o[0 * NS] = ua[0];
    o[1 * NS] = ua[1];
    o[2 * NS] = ua[2];
    o[3 * NS] = ua[3];
    o[4 * NS] = ua[4];
}

// ---------------------------------------------------------------------------
// KF: g_j = conv_b[127] + sum_k u[j+k][k]; leaky; y = lin_b + sum_j lw[j]*g_j
// ---------------------------------------------------------------------------
__global__ __launch_bounds__(256) void k_final(const float* __restrict__ uT,
                                               const float* __restrict__ cb,
                                               const float* __restrict__ lw,
                                               const float* __restrict__ lb,
                                               float* __restrict__ outp) {
    int n = blockIdx.x * 256 + threadIdx.x;
    if (n >= NS) return;
    float b127 = cb[127];
    float acc = lb[0];
#pragma unroll
    for (int j = 0; j < 36; j++) {
        float g = b127;
#pragma unroll
        for (int k = 0; k < 5; k++) {
            g += uT[(size_t)((j + k) * 5 + k) * NS + n];
        }
        g = (g >= 0.0f) ? g : 0.01f * g;
        acc += g * lw[j];
    }
    outp[n] = acc;
}

// ---------------------------------------------------------------------------
extern "C" void kernel_launch(void* const* d_in, const int* in_sizes, int n_in,
                              void* d_out, int out_size, void* d_ws, size_t ws_size,
                              hipStream_t stream) {
    const float* x  = (const float*)d_in[0];   // [8000,64,64]
    const float* cw = (const float*)d_in[1];   // [128,144,5]
    const float* cb = (const float*)d_in[2];   // [128]
    const float* lw = (const float*)d_in[3];   // [1,36]
    const float* lb = (const float*)d_in[4];   // [1]
    float* outp = (float*)d_out;               // [8000,1]

    float* ws    = (float*)d_ws;
    float* xeT   = ws;                         // 8*59*8000
    float* rankT = ws + XET_SZ;                // 8*40*8000
    float* uT    = ws + XET_SZ + RNK_SZ;       // 40*5*8000

    k_transpose<<<dim3(32, 59), 256, 0, stream>>>(x, xeT);
    k_rank<<<dim3(WIN, EE), 256, 0, stream>>>(xeT, rankT);
    k_stats<<<dim3(125, WIN), 64, 0, stream>>>(x, cw, xeT, rankT, uT);
    k_final<<<32, 256, 0, stream>>>(uT, cb, lw, lb, outp);
}

// Round 2
// 276.723 us; speedup vs baseline: 1.1960x; 1.1960x over previous
//
#include <hip/hip_runtime.h>
#include <math.h>

// Problem constants
#define NS    8000      // N samples
#define TT    64        // T
#define FF    64        // F
#define EE    8         // E
#define WIN   40        // WINDOW
#define TR    59        // rows of xe kept: t = 5..63
#define NBINS 1024

// ws layout (floats):
//   xeT  [8][59][8000]  = 3,776,000
//   rankT[8][40][8000]  = 2,560,000
//   uT   [40][5][8000]  = 1,600,000
#define XET_SZ  (8*59*8000)
#define RNK_SZ  (8*40*8000)

// ---------------------------------------------------------------------------
// K0: transpose x[:, 5:64, 0:8] -> xeT[e][r][n]  (r = t-5)
// ---------------------------------------------------------------------------
__global__ __launch_bounds__(256) void k_transpose(const float* __restrict__ x,
                                                   float* __restrict__ xeT) {
    int n = blockIdx.x * 256 + threadIdx.x;
    int r = blockIdx.y;              // 0..58
    if (n >= NS) return;
    const float* row = x + (size_t)n * (TT * FF) + (5 + r) * FF;
    float4 a = *(const float4*)(row);
    float4 b = *(const float4*)(row + 4);
    xeT[(0 * TR + r) * NS + n] = a.x;
    xeT[(1 * TR + r) * NS + n] = a.y;
    xeT[(2 * TR + r) * NS + n] = a.z;
    xeT[(3 * TR + r) * NS + n] = a.w;
    xeT[(4 * TR + r) * NS + n] = b.x;
    xeT[(5 * TR + r) * NS + n] = b.y;
    xeT[(6 * TR + r) * NS + n] = b.z;
    xeT[(7 * TR + r) * NS + n] = b.w;
}

// ---------------------------------------------------------------------------
// KR: exact cross-batch descending rank (stable ties by index) per column.
// One block per (w,e), 1024 threads (16 waves) -> 2 blocks/CU (60KB LDS) =
// 32 waves/CU for latency hiding. Bucketed counting over [-4,4], histogram,
// suffix offsets, scatter, exact within-bucket comparison.
// ---------------------------------------------------------------------------
__device__ __forceinline__ int binOf(float v) {
    int b = (int)((v + 4.0f) * 128.0f);   // monotone; trunc ok (clamped)
    b = b < 0 ? 0 : b;
    return b > (NBINS - 1) ? (NBINS - 1) : b;
}

__global__ __launch_bounds__(1024) void k_rank(const float* __restrict__ xeT,
                                               float* __restrict__ rankT) {
    const int w = blockIdx.x;   // 0..39
    const int e = blockIdx.y;   // 0..7
    __shared__ unsigned hist[NBINS];     // later reused as scatter cursor
    __shared__ unsigned basev[NBINS];    // # elements in strictly greater buckets
    __shared__ unsigned bendv[NBINS];    // basev + bucket count
    __shared__ float          sk[NS];    // scattered values (bucket-grouped)
    __shared__ unsigned short si[NS];    // scattered original indices
    __shared__ unsigned wsum[16];

    const int tid  = threadIdx.x;
    const int lane = tid & 63;
    const int wid  = tid >> 6;
    const float* col = xeT + ((size_t)e * TR + (19 + w)) * NS;   // t = 24+w

    float val[8];
#pragma unroll
    for (int i = 0; i < 8; i++) {
        int idx = tid + i * 1024;
        val[i] = (idx < NS) ? col[idx] : 0.0f;
    }
    hist[tid] = 0;
    __syncthreads();

#pragma unroll
    for (int i = 0; i < 8; i++) {
        int idx = tid + i * 1024;
        if (idx < NS) atomicAdd(&hist[binOf(val[i])], 1u);
    }
    __syncthreads();

    // suffix offsets: 1 bin per thread; wave scan + cross-wave offsets
    unsigned h = hist[tid];
    unsigned sc = h;
#pragma unroll
    for (int d = 1; d < 64; d <<= 1) {
        unsigned t2 = __shfl_up(sc, d);
        if (lane >= d) sc += t2;
    }
    if (lane == 63) wsum[wid] = sc;
    __syncthreads();
    unsigned woff = 0;
    for (int i = 0; i < wid; i++) woff += wsum[i];
    unsigned before = woff + (sc - h);   // # elements in buckets < tid
    bendv[tid] = NS - before;            // base + count
    basev[tid] = NS - before - h;        // # strictly greater
    hist[tid]  = NS - before - h;        // scatter cursor
    __syncthreads();

    // scatter into bucket-grouped order (order within bucket irrelevant)
#pragma unroll
    for (int i = 0; i < 8; i++) {
        int idx = tid + i * 1024;
        if (idx < NS) {
            int b = binOf(val[i]);
            unsigned p = atomicAdd(&hist[b], 1u);
            sk[p] = val[i];
            si[p] = (unsigned short)idx;
        }
    }
    __syncthreads();

    // exact rank: greater buckets + within-bucket (value desc, index asc)
    float* outp = rankT + ((size_t)e * WIN + w) * NS;
#pragma unroll 1
    for (int i = 0; i < 8; i++) {
        int p = tid + i * 1024;
        if (p < NS) {
            float v = sk[p];
            unsigned idm = si[p];
            int b = binOf(v);
            unsigned lo = basev[b], hi = bendv[b];
            unsigned c = 0;
            for (unsigned q = lo; q < hi; q++) {
                float u2 = sk[q];
                c += (u2 > v) || (u2 == v && si[q] < idm);
            }
            outp[idm] = (float)(basev[b] + c) / 8000.0f;
        }
    }
}

// ---------------------------------------------------------------------------
// KS: per thread: one n, a chunk of 4 windows. Loads 23 xeT values per e
// (sliding windows share registers), folds stats + rank + raw channels
// straight into conv ch-127 partials u[w][k].
// ---------------------------------------------------------------------------
__global__ __launch_bounds__(128) void k_stats(const float* __restrict__ x,
                                               const float* __restrict__ cw,
                                               const float* __restrict__ xeT,
                                               const float* __restrict__ rankT,
                                               float* __restrict__ uT) {
    const int n  = blockIdx.x * 128 + threadIdx.x;
    const int w0 = blockIdx.y * 4;                 // 0,4,...,36
    if (n >= NS) return;
    const float* W = cw + 127 * 144 * 5;           // only out-channel 127 used

    float g[4][5];
#pragma unroll
    for (int dw = 0; dw < 4; dw++)
#pragma unroll
        for (int k = 0; k < 5; k++) g[dw][k] = 0.0f;

    // raw channels 0..63: x[n, 24+w0+dw, f]
    {
        const float* row = x + (size_t)n * (TT * FF) + (24 + w0) * FF;
#pragma unroll
        for (int dw = 0; dw < 4; dw++) {
            const float* r2 = row + dw * FF;
#pragma unroll
            for (int f = 0; f < FF; f += 4) {
                float4 a = *(const float4*)(r2 + f);
#pragma unroll
                for (int k = 0; k < 5; k++) {
                    g[dw][k] += a.x * W[(f + 0) * 5 + k] + a.y * W[(f + 1) * 5 + k]
                              + a.z * W[(f + 2) * 5 + k] + a.w * W[(f + 3) * 5 + k];
                }
            }
        }
    }

    // derived channels: week block 64..103, month block 104..143
    for (int e = 0; e < 8; e++) {
        const float* colbase = xeT + ((size_t)e * TR + w0) * NS + n;
        float xv[23];
#pragma unroll
        for (int j = 0; j < 23; j++) xv[j] = colbase[(size_t)j * NS];

#pragma unroll
        for (int dw = 0; dw < 4; dw++) {
            float s20 = 0.f, mn20 = xv[dw], mx20 = xv[dw];
#pragma unroll
            for (int i = 0; i < 20; i++) {
                float v = xv[dw + i];
                s20 += v; mn20 = fminf(mn20, v); mx20 = fmaxf(mx20, v);
            }
            float m20 = s20 * (1.0f / 20.0f);
            float d20 = 0.f;
#pragma unroll
            for (int i = 0; i < 20; i++) { float t = xv[dw + i] - m20; d20 += t * t; }
            float sd20 = sqrtf(d20 * (1.0f / 19.0f));

            float s5 = 0.f, mn5 = xv[dw + 15], mx5 = xv[dw + 15];
#pragma unroll
            for (int i = 15; i < 20; i++) {
                float v = xv[dw + i];
                s5 += v; mn5 = fminf(mn5, v); mx5 = fmaxf(mx5, v);
            }
            float m5 = s5 * 0.2f;
            float d5 = 0.f;
#pragma unroll
            for (int i = 15; i < 20; i++) { float t = xv[dw + i] - m5; d5 += t * t; }
            float sd5 = sqrtf(d5 * 0.25f);

            float rk = rankT[((size_t)e * WIN + (w0 + dw)) * NS + n];

#pragma unroll
            for (int k = 0; k < 5; k++) {
                float uk;
                uk  = m5   * W[(64  + e) * 5 + k];
                uk += sd5  * W[(72  + e) * 5 + k];
                uk += rk   * (W[(80 + e) * 5 + k] + W[(120 + e) * 5 + k]);
                uk += mx5  * W[(88  + e) * 5 + k];
                uk += mn5  * W[(96  + e) * 5 + k];
                uk += m20  * W[(104 + e) * 5 + k];
                uk += sd20 * W[(112 + e) * 5 + k];
                uk += mx20 * W[(128 + e) * 5 + k];
                uk += mn20 * W[(136 + e) * 5 + k];
                g[dw][k] += uk;
            }
        }
    }

    // uT[w][k][n]
#pragma unroll
    for (int dw = 0; dw < 4; dw++)
#pragma unroll
        for (int k = 0; k < 5; k++)
            uT[(size_t)((w0 + dw) * 5 + k) * NS + n] = g[dw][k];
}

// ---------------------------------------------------------------------------
// KF: g_j = conv_b[127] + sum_k u[j+k][k]; leaky; y = lin_b + sum_j lw[j]*g_j
// ---------------------------------------------------------------------------
__global__ __launch_bounds__(256) void k_final(const float* __restrict__ uT,
                                               const float* __restrict__ cb,
                                               const float* __restrict__ lw,
                                               const float* __restrict__ lb,
                                               float* __restrict__ outp) {
    int n = blockIdx.x * 256 + threadIdx.x;
    if (n >= NS) return;
    float b127 = cb[127];
    float acc = lb[0];
#pragma unroll
    for (int j = 0; j < 36; j++) {
        float g = b127;
#pragma unroll
        for (int k = 0; k < 5; k++) {
            g += uT[(size_t)((j + k) * 5 + k) * NS + n];
        }
        g = (g >= 0.0f) ? g : 0.01f * g;
        acc += g * lw[j];
    }
    outp[n] = acc;
}

// ---------------------------------------------------------------------------
extern "C" void kernel_launch(void* const* d_in, const int* in_sizes, int n_in,
                              void* d_out, int out_size, void* d_ws, size_t ws_size,
                              hipStream_t stream) {
    const float* x  = (const float*)d_in[0];   // [8000,64,64]
    const float* cw = (const float*)d_in[1];   // [128,144,5]
    const float* cb = (const float*)d_in[2];   // [128]
    const float* lw = (const float*)d_in[3];   // [1,36]
    const float* lb = (const float*)d_in[4];   // [1]
    float* outp = (float*)d_out;               // [8000,1]

    float* ws    = (float*)d_ws;
    float* xeT   = ws;                         // 8*59*8000
    float* rankT = ws + XET_SZ;                // 8*40*8000
    float* uT    = ws + XET_SZ + RNK_SZ;       // 40*5*8000

    k_transpose<<<dim3(32, 59), 256, 0, stream>>>(x, xeT);
    k_rank<<<dim3(WIN, EE), 1024, 0, stream>>>(xeT, rankT);
    k_stats<<<dim3(63, 10), 128, 0, stream>>>(x, cw, xeT, rankT, uT);
    k_final<<<32, 256, 0, stream>>>(uT, cb, lw, lb, outp);
}

// Round 3
// 269.589 us; speedup vs baseline: 1.2276x; 1.0265x over previous
//
#include <hip/hip_runtime.h>
#include <math.h>

// Problem constants
#define NS    8000      // N samples
#define TT    64        // T
#define FF    64        // F
#define EE    8         // E
#define WIN   40        // WINDOW
#define TR    59        // rows of xe kept: t = 5..63
#define NBINS 1024

// ws layout (floats):
//   xeT  [8][59][8000]  = 3,776,000
//   rankT[8][40][8000]  = 2,560,000
//   uder [40][5][8000]  = 1,600,000
//   uraw [8000][40][5]  = 1,600,000
#define XET_SZ  (8*59*8000)
#define RNK_SZ  (8*40*8000)
#define UDER_SZ (40*5*8000)

// ---------------------------------------------------------------------------
// K0: transpose x[:, 5:64, 0:8] -> xeT[e][r][n]  (r = t-5)
// ---------------------------------------------------------------------------
__global__ __launch_bounds__(256) void k_transpose(const float* __restrict__ x,
                                                   float* __restrict__ xeT) {
    int n = blockIdx.x * 256 + threadIdx.x;
    int r = blockIdx.y;              // 0..58
    if (n >= NS) return;
    const float* row = x + (size_t)n * (TT * FF) + (5 + r) * FF;
    float4 a = *(const float4*)(row);
    float4 b = *(const float4*)(row + 4);
    xeT[(0 * TR + r) * NS + n] = a.x;
    xeT[(1 * TR + r) * NS + n] = a.y;
    xeT[(2 * TR + r) * NS + n] = a.z;
    xeT[(3 * TR + r) * NS + n] = a.w;
    xeT[(4 * TR + r) * NS + n] = b.x;
    xeT[(5 * TR + r) * NS + n] = b.y;
    xeT[(6 * TR + r) * NS + n] = b.z;
    xeT[(7 * TR + r) * NS + n] = b.w;
}

// ---------------------------------------------------------------------------
// KR: exact cross-batch descending rank (stable ties by index) per column.
// One block per (w,e), 1024 threads, 60.4KB LDS -> 2 blocks/CU = 32 waves/CU.
// ---------------------------------------------------------------------------
__device__ __forceinline__ int binOf(float v) {
    int b = (int)((v + 4.0f) * 128.0f);   // monotone; trunc ok (clamped)
    b = b < 0 ? 0 : b;
    return b > (NBINS - 1) ? (NBINS - 1) : b;
}

__global__ __launch_bounds__(1024) void k_rank(const float* __restrict__ xeT,
                                               float* __restrict__ rankT) {
    const int w = blockIdx.x;   // 0..39
    const int e = blockIdx.y;   // 0..7
    __shared__ unsigned hist[NBINS];     // later reused as scatter cursor
    __shared__ unsigned basev[NBINS];    // # elements in strictly greater buckets
    __shared__ unsigned bendv[NBINS];    // basev + bucket count
    __shared__ float          sk[NS];    // scattered values (bucket-grouped)
    __shared__ unsigned short si[NS];    // scattered original indices
    __shared__ unsigned wsum[16];

    const int tid  = threadIdx.x;
    const int lane = tid & 63;
    const int wid  = tid >> 6;
    const float* col = xeT + ((size_t)e * TR + (19 + w)) * NS;   // t = 24+w

    float val[8];
#pragma unroll
    for (int i = 0; i < 8; i++) {
        int idx = tid + i * 1024;
        val[i] = (idx < NS) ? col[idx] : 0.0f;
    }
    hist[tid] = 0;
    __syncthreads();

#pragma unroll
    for (int i = 0; i < 8; i++) {
        int idx = tid + i * 1024;
        if (idx < NS) atomicAdd(&hist[binOf(val[i])], 1u);
    }
    __syncthreads();

    // suffix offsets: 1 bin per thread; wave scan + cross-wave offsets
    unsigned h = hist[tid];
    unsigned sc = h;
#pragma unroll
    for (int d = 1; d < 64; d <<= 1) {
        unsigned t2 = __shfl_up(sc, d);
        if (lane >= d) sc += t2;
    }
    if (lane == 63) wsum[wid] = sc;
    __syncthreads();
    unsigned woff = 0;
    for (int i = 0; i < wid; i++) woff += wsum[i];
    unsigned before = woff + (sc - h);   // # elements in buckets < tid
    bendv[tid] = NS - before;            // base + count
    basev[tid] = NS - before - h;        // # strictly greater
    hist[tid]  = NS - before - h;        // scatter cursor
    __syncthreads();

    // scatter into bucket-grouped order (order within bucket irrelevant)
#pragma unroll
    for (int i = 0; i < 8; i++) {
        int idx = tid + i * 1024;
        if (idx < NS) {
            int b = binOf(val[i]);
            unsigned p = atomicAdd(&hist[b], 1u);
            sk[p] = val[i];
            si[p] = (unsigned short)idx;
        }
    }
    __syncthreads();

    // exact rank: greater buckets + within-bucket (value desc, index asc).
    // p consecutive -> lanes share buckets -> LDS reads broadcast.
    float* outp = rankT + ((size_t)e * WIN + w) * NS;
#pragma unroll 1
    for (int i = 0; i < 8; i++) {
        int p = tid + i * 1024;
        if (p < NS) {
            float v = sk[p];
            unsigned idm = si[p];
            int b = binOf(v);
            unsigned lo = basev[b], hi = bendv[b];
            unsigned c = 0;
            for (unsigned q = lo; q < hi; q++) {
                float u2 = sk[q];
                c += (u2 > v) || (u2 == v && si[q] < idm);
            }
            outp[idm] = (float)(basev[b] + c) / 8000.0f;
        }
    }
}

// ---------------------------------------------------------------------------
// KRaw: raw-channel conv fold. One wave per n. Lane = (g,l): group g of 4
// windows, lane-quad l of features. Each wave iteration loads 1KB contiguous
// (4 windows x 256B rows) via one dwordx4; 20 FMA/lane; 4-step shfl_xor
// reduce within 16-lane groups; lanes 0..4 of each group store u[n][w][0..4].
// ---------------------------------------------------------------------------
__global__ __launch_bounds__(256) void k_raw(const float* __restrict__ x,
                                             const float* __restrict__ cw,
                                             float* __restrict__ uraw) {
    const int n    = blockIdx.x * 4 + (threadIdx.x >> 6);   // 2000*4 = 8000
    const int lane = threadIdx.x & 63;
    const int g    = lane >> 4;      // window subgroup 0..3
    const int l    = lane & 15;      // feature quad 0..15
    const float* W = cw + 127 * 144 * 5;

    // lane's weights: W[c][k] for c = 4l..4l+3, k=0..4 -> 20 consecutive
    // floats at W + l*20 (80B-aligned)
    float wreg[20];
    {
        const float4* Wq = (const float4*)(W + l * 20);
#pragma unroll
        for (int q = 0; q < 5; q++) {
            float4 t = Wq[q];
            wreg[q * 4 + 0] = t.x; wreg[q * 4 + 1] = t.y;
            wreg[q * 4 + 2] = t.z; wreg[q * 4 + 3] = t.w;
        }
    }

    const float* xbase = x + (size_t)n * (TT * FF) + 24 * FF + l * 4;
    float* ubase = uraw + (size_t)n * (WIN * 5);

#pragma unroll 1
    for (int w0 = 0; w0 < WIN; w0 += 4) {
        const int w = w0 + g;
        float4 xv = *(const float4*)(xbase + w * FF);
        float acc[5];
#pragma unroll
        for (int k = 0; k < 5; k++) {
            acc[k] = xv.x * wreg[0 * 5 + k] + xv.y * wreg[1 * 5 + k]
                   + xv.z * wreg[2 * 5 + k] + xv.w * wreg[3 * 5 + k];
        }
#pragma unroll
        for (int d = 1; d < 16; d <<= 1) {
#pragma unroll
            for (int k = 0; k < 5; k++) acc[k] += __shfl_xor(acc[k], d, 64);
        }
        if (l < 5) {
            float v = acc[0];
            if (l == 1) v = acc[1];
            else if (l == 2) v = acc[2];
            else if (l == 3) v = acc[3];
            else if (l == 4) v = acc[4];
            ubase[w * 5 + l] = v;   // 20 consecutive dwords active per wave
        }
    }
}

// ---------------------------------------------------------------------------
// KDer: derived channels only. Thread per (n,w); all loads coalesced.
// ---------------------------------------------------------------------------
__global__ __launch_bounds__(256) void k_der(const float* __restrict__ cw,
                                             const float* __restrict__ xeT,
                                             const float* __restrict__ rankT,
                                             float* __restrict__ uder) {
    const int n = blockIdx.x * 256 + threadIdx.x;
    const int w = blockIdx.y;                      // 0..39
    if (n >= NS) return;
    const float* W = cw + 127 * 144 * 5;

    float g[5] = {0.f, 0.f, 0.f, 0.f, 0.f};

    for (int e = 0; e < 8; e++) {
        const float* colbase = xeT + ((size_t)e * TR + w) * NS + n;
        float xv[20];
#pragma unroll
        for (int j = 0; j < 20; j++) xv[j] = colbase[(size_t)j * NS];

        float s20 = 0.f, mn20 = xv[0], mx20 = xv[0];
#pragma unroll
        for (int i = 0; i < 20; i++) {
            float v = xv[i];
            s20 += v; mn20 = fminf(mn20, v); mx20 = fmaxf(mx20, v);
        }
        float m20 = s20 * (1.0f / 20.0f);
        float d20 = 0.f;
#pragma unroll
        for (int i = 0; i < 20; i++) { float t = xv[i] - m20; d20 += t * t; }
        float sd20 = sqrtf(d20 * (1.0f / 19.0f));

        float s5 = 0.f, mn5 = xv[15], mx5 = xv[15];
#pragma unroll
        for (int i = 15; i < 20; i++) {
            float v = xv[i];
            s5 += v; mn5 = fminf(mn5, v); mx5 = fmaxf(mx5, v);
        }
        float m5 = s5 * 0.2f;
        float d5 = 0.f;
#pragma unroll
        for (int i = 15; i < 20; i++) { float t = xv[i] - m5; d5 += t * t; }
        float sd5 = sqrtf(d5 * 0.25f);

        float rk = rankT[((size_t)e * WIN + w) * NS + n];

#pragma unroll
        for (int k = 0; k < 5; k++) {
            float uk;
            uk  = m5   * W[(64  + e) * 5 + k];
            uk += sd5  * W[(72  + e) * 5 + k];
            uk += rk   * (W[(80 + e) * 5 + k] + W[(120 + e) * 5 + k]);
            uk += mx5  * W[(88  + e) * 5 + k];
            uk += mn5  * W[(96  + e) * 5 + k];
            uk += m20  * W[(104 + e) * 5 + k];
            uk += sd20 * W[(112 + e) * 5 + k];
            uk += mx20 * W[(128 + e) * 5 + k];
            uk += mn20 * W[(136 + e) * 5 + k];
            g[k] += uk;
        }
    }

#pragma unroll
    for (int k = 0; k < 5; k++)
        uder[(size_t)(w * 5 + k) * NS + n] = g[k];
}

// ---------------------------------------------------------------------------
// KF: g_j = conv_b[127] + sum_k (uraw+uder); leaky; y = lin_b + sum lw[j]*g_j
// ---------------------------------------------------------------------------
__global__ __launch_bounds__(256) void k_final(const float* __restrict__ uraw,
                                               const float* __restrict__ uder,
                                               const float* __restrict__ cb,
                                               const float* __restrict__ lw,
                                               const float* __restrict__ lb,
                                               float* __restrict__ outp) {
    int n = blockIdx.x * 256 + threadIdx.x;
    if (n >= NS) return;
    float b127 = cb[127];
    float acc = lb[0];
    const float* ur = uraw + (size_t)n * (WIN * 5);
#pragma unroll
    for (int j = 0; j < 36; j++) {
        float g = b127;
#pragma unroll
        for (int k = 0; k < 5; k++) {
            int c = (j + k) * 5 + k;
            g += ur[c] + uder[(size_t)c * NS + n];
        }
        g = (g >= 0.0f) ? g : 0.01f * g;
        acc += g * lw[j];
    }
    outp[n] = acc;
}

// ---------------------------------------------------------------------------
extern "C" void kernel_launch(void* const* d_in, const int* in_sizes, int n_in,
                              void* d_out, int out_size, void* d_ws, size_t ws_size,
                              hipStream_t stream) {
    const float* x  = (const float*)d_in[0];   // [8000,64,64]
    const float* cw = (const float*)d_in[1];   // [128,144,5]
    const float* cb = (const float*)d_in[2];   // [128]
    const float* lw = (const float*)d_in[3];   // [1,36]
    const float* lb = (const float*)d_in[4];   // [1]
    float* outp = (float*)d_out;               // [8000,1]

    float* ws    = (float*)d_ws;
    float* xeT   = ws;                                   // 8*59*8000
    float* rankT = ws + XET_SZ;                          // 8*40*8000
    float* uder  = ws + XET_SZ + RNK_SZ;                 // 40*5*8000
    float* uraw  = ws + XET_SZ + RNK_SZ + UDER_SZ;       // 8000*40*5

    k_transpose<<<dim3(32, 59), 256, 0, stream>>>(x, xeT);
    k_rank<<<dim3(WIN, EE), 1024, 0, stream>>>(xeT, rankT);
    k_raw<<<2000, 256, 0, stream>>>(x, cw, uraw);
    k_der<<<dim3(32, WIN), 256, 0, stream>>>(cw, xeT, rankT, uder);
    k_final<<<32, 256, 0, stream>>>(uraw, uder, cb, lw, lb, outp);
}

// Round 4
// 252.966 us; speedup vs baseline: 1.3083x; 1.0657x over previous
//
#include <hip/hip_runtime.h>
#include <math.h>

// Problem constants
#define NS    8000      // N samples
#define TT    64        // T
#define FF    64        // F
#define EE    8         // E
#define WIN   40        // WINDOW
#define TR    59        // rows of xe kept: t = 5..63
#define NBINS 2048

// ws layout (floats):
//   xeT  [8][59][8000]  = 3,776,000
//   rankT[8][40][8000]  = 2,560,000
//   uraw [8000][40][5]  = 1,600,000
#define XET_SZ  (8*59*8000)
#define RNK_SZ  (8*40*8000)

// ---------------------------------------------------------------------------
// K0: transpose x[:, 5:64, 0:8] -> xeT[e][r][n]  (r = t-5)
// ---------------------------------------------------------------------------
__global__ __launch_bounds__(256) void k_transpose(const float* __restrict__ x,
                                                   float* __restrict__ xeT) {
    int n = blockIdx.x * 256 + threadIdx.x;
    int r = blockIdx.y;              // 0..58
    if (n >= NS) return;
    const float* row = x + (size_t)n * (TT * FF) + (5 + r) * FF;
    float4 a = *(const float4*)(row);
    float4 b = *(const float4*)(row + 4);
    xeT[(0 * TR + r) * NS + n] = a.x;
    xeT[(1 * TR + r) * NS + n] = a.y;
    xeT[(2 * TR + r) * NS + n] = a.z;
    xeT[(3 * TR + r) * NS + n] = a.w;
    xeT[(4 * TR + r) * NS + n] = b.x;
    xeT[(5 * TR + r) * NS + n] = b.y;
    xeT[(6 * TR + r) * NS + n] = b.z;
    xeT[(7 * TR + r) * NS + n] = b.w;
}

// ---------------------------------------------------------------------------
// KR: exact cross-batch descending rank (stable ties by index) per column.
// One block per (w,e), 1024 threads. 2048 bins over [-4,4] -> ~9 avg
// within-bucket comparisons. LDS 72.6KB -> 2 blocks/CU = 32 waves/CU.
// ---------------------------------------------------------------------------
__device__ __forceinline__ int binOf(float v) {
    int b = (int)((v + 4.0f) * 256.0f);   // monotone; trunc ok (clamped)
    b = b < 0 ? 0 : b;
    return b > (NBINS - 1) ? (NBINS - 1) : b;
}

__global__ __launch_bounds__(1024) void k_rank(const float* __restrict__ xeT,
                                               float* __restrict__ rankT) {
    const int w = blockIdx.x;   // 0..39
    const int e = blockIdx.y;   // 0..7
    __shared__ unsigned hist[NBINS];     // later reused as scatter cursor
    __shared__ unsigned basev[NBINS];    // # elements in strictly greater buckets
    __shared__ unsigned bendv[NBINS];    // basev + bucket count
    __shared__ float          sk[NS];    // scattered values (bucket-grouped)
    __shared__ unsigned short si[NS];    // scattered original indices
    __shared__ unsigned wsum[16];

    const int tid  = threadIdx.x;
    const int lane = tid & 63;
    const int wid  = tid >> 6;
    const float* col = xeT + ((size_t)e * TR + (19 + w)) * NS;   // t = 24+w

    float val[8];
#pragma unroll
    for (int i = 0; i < 8; i++) {
        int idx = tid + i * 1024;
        val[i] = (idx < NS) ? col[idx] : 0.0f;
    }
    hist[tid] = 0;
    hist[tid + 1024] = 0;
    __syncthreads();

#pragma unroll
    for (int i = 0; i < 8; i++) {
        int idx = tid + i * 1024;
        if (idx < NS) atomicAdd(&hist[binOf(val[i])], 1u);
    }
    __syncthreads();

    // suffix offsets: 2 bins per thread; wave scan + cross-wave offsets
    unsigned h0 = hist[2 * tid + 0];
    unsigned h1 = hist[2 * tid + 1];
    unsigned cs = h0 + h1;
    unsigned sc = cs;
#pragma unroll
    for (int d = 1; d < 64; d <<= 1) {
        unsigned t2 = __shfl_up(sc, d);
        if (lane >= d) sc += t2;
    }
    if (lane == 63) wsum[wid] = sc;
    __syncthreads();
    unsigned woff = 0;
    for (int i = 0; i < wid; i++) woff += wsum[i];
    unsigned before = woff + (sc - cs);   // # elements in bins < 2*tid
    {
        int b = 2 * tid;
        bendv[b] = NS - before; before += h0; basev[b] = NS - before;
        hist[b] = basev[b];  b++;
        bendv[b] = NS - before; before += h1; basev[b] = NS - before;
        hist[b] = basev[b];
    }
    __syncthreads();

    // scatter into bucket-grouped order (order within bucket irrelevant)
#pragma unroll
    for (int i = 0; i < 8; i++) {
        int idx = tid + i * 1024;
        if (idx < NS) {
            int b = binOf(val[i]);
            unsigned p = atomicAdd(&hist[b], 1u);
            sk[p] = val[i];
            si[p] = (unsigned short)idx;
        }
    }
    __syncthreads();

    // exact rank: greater buckets + within-bucket (value desc, index asc).
    // p consecutive -> lanes share buckets -> LDS reads broadcast.
    float* outp = rankT + ((size_t)e * WIN + w) * NS;
#pragma unroll 1
    for (int i = 0; i < 8; i++) {
        int p = tid + i * 1024;
        if (p < NS) {
            float v = sk[p];
            unsigned idm = si[p];
            int b = binOf(v);
            unsigned lo = basev[b], hi = bendv[b];
            unsigned c = 0;
            for (unsigned q = lo; q < hi; q++) {
                float u2 = sk[q];
                c += (u2 > v) || (u2 == v && si[q] < idm);
            }
            outp[idm] = (float)(basev[b] + c) / 8000.0f;
        }
    }
}

// ---------------------------------------------------------------------------
// KRaw: raw-channel conv fold. One wave per n; lane=(g,l): window group g,
// feature quad l. 1KB contiguous per wave-load; shfl_xor reduce; lanes 0..4
// of each 16-group store uraw[n][w][0..4].
// ---------------------------------------------------------------------------
__global__ __launch_bounds__(256) void k_raw(const float* __restrict__ x,
                                             const float* __restrict__ cw,
                                             float* __restrict__ uraw) {
    const int n    = blockIdx.x * 4 + (threadIdx.x >> 6);   // 2000*4 = 8000
    const int lane = threadIdx.x & 63;
    const int g    = lane >> 4;      // window subgroup 0..3
    const int l    = lane & 15;      // feature quad 0..15
    const float* W = cw + 127 * 144 * 5;

    float wreg[20];
    {
        const float4* Wq = (const float4*)(W + l * 20);
#pragma unroll
        for (int q = 0; q < 5; q++) {
            float4 t = Wq[q];
            wreg[q * 4 + 0] = t.x; wreg[q * 4 + 1] = t.y;
            wreg[q * 4 + 2] = t.z; wreg[q * 4 + 3] = t.w;
        }
    }

    const float* xbase = x + (size_t)n * (TT * FF) + 24 * FF + l * 4;
    float* ubase = uraw + (size_t)n * (WIN * 5);

#pragma unroll 1
    for (int w0 = 0; w0 < WIN; w0 += 4) {
        const int w = w0 + g;
        float4 xv = *(const float4*)(xbase + w * FF);
        float acc[5];
#pragma unroll
        for (int k = 0; k < 5; k++) {
            acc[k] = xv.x * wreg[0 * 5 + k] + xv.y * wreg[1 * 5 + k]
                   + xv.z * wreg[2 * 5 + k] + xv.w * wreg[3 * 5 + k];
        }
#pragma unroll
        for (int d = 1; d < 16; d <<= 1) {
#pragma unroll
            for (int k = 0; k < 5; k++) acc[k] += __shfl_xor(acc[k], d, 64);
        }
        if (l < 5) {
            float v = acc[0];
            if (l == 1) v = acc[1];
            else if (l == 2) v = acc[2];
            else if (l == 3) v = acc[3];
            else if (l == 4) v = acc[4];
            ubase[w * 5 + l] = v;
        }
    }
}

// ---------------------------------------------------------------------------
// KDF: fused derived-stats + conv-fold + epilogue. Thread = (n,e); 20-reg
// sliding ring over 59 xeT rows (xeT read exactly once). Per-thread partial
// gder[36]; LDS e-reduction ([8][32][37], conflict-free); 32 threads do the
// leaky+dot epilogue per block.
// ---------------------------------------------------------------------------
__global__ __launch_bounds__(256) void k_der_final(const float* __restrict__ cw,
                                                   const float* __restrict__ xeT,
                                                   const float* __restrict__ rankT,
                                                   const float* __restrict__ uraw,
                                                   const float* __restrict__ cb,
                                                   const float* __restrict__ lw,
                                                   const float* __restrict__ lb,
                                                   float* __restrict__ outp) {
    __shared__ float red[8][32][37];
    const int tid = threadIdx.x;
    const int e   = tid >> 5;          // 0..7
    const int nl  = tid & 31;          // 0..31
    const int n0  = blockIdx.x * 32;   // 250 blocks * 32 = 8000
    const int n   = n0 + nl;
    const float* W = cw + 127 * 144 * 5;

    float gder[36];
#pragma unroll
    for (int j = 0; j < 36; j++) gder[j] = 0.0f;

    const float* col = xeT + (size_t)e * TR * NS + n;
    const float* rkp = rankT + (size_t)e * WIN * NS + n;

    float ring[20];
#pragma unroll
    for (int r = 0; r < 19; r++) ring[r] = col[(size_t)r * NS];

#pragma unroll
    for (int w = 0; w < WIN; w++) {
        ring[(w + 19) % 20] = col[(size_t)(w + 19) * NS];
        // window = rows w..w+19 (all 20 ring slots); order irrelevant
        float s20 = 0.f, mn20 = ring[0], mx20 = ring[0];
#pragma unroll
        for (int i = 0; i < 20; i++) {
            float v = ring[i];
            s20 += v; mn20 = fminf(mn20, v); mx20 = fmaxf(mx20, v);
        }
        float m20 = s20 * (1.0f / 20.0f);
        float d20 = 0.f;
#pragma unroll
        for (int i = 0; i < 20; i++) { float t = ring[i] - m20; d20 += t * t; }
        float sd20 = sqrtf(d20 * (1.0f / 19.0f));

        // week = rows w+15..w+19
        float s5 = 0.f, mn5 = ring[(w + 15) % 20], mx5 = mn5;
#pragma unroll
        for (int i = 15; i < 20; i++) {
            float v = ring[(w + i) % 20];
            s5 += v; mn5 = fminf(mn5, v); mx5 = fmaxf(mx5, v);
        }
        float m5 = s5 * 0.2f;
        float d5 = 0.f;
#pragma unroll
        for (int i = 15; i < 20; i++) {
            float t = ring[(w + i) % 20] - m5; d5 += t * t;
        }
        float sd5 = sqrtf(d5 * 0.25f);

        float rk = rkp[(size_t)w * NS];

#pragma unroll
        for (int k = 0; k < 5; k++) {
            int j = w - k;
            if (j >= 0 && j < 36) {
                float uk;
                uk  = m5   * W[(64  + e) * 5 + k];
                uk += sd5  * W[(72  + e) * 5 + k];
                uk += rk   * (W[(80 + e) * 5 + k] + W[(120 + e) * 5 + k]);
                uk += mx5  * W[(88  + e) * 5 + k];
                uk += mn5  * W[(96  + e) * 5 + k];
                uk += m20  * W[(104 + e) * 5 + k];
                uk += sd20 * W[(112 + e) * 5 + k];
                uk += mx20 * W[(128 + e) * 5 + k];
                uk += mn20 * W[(136 + e) * 5 + k];
                gder[j] += uk;
            }
        }
    }

    // stage partials: red[e][nl][j]; consecutive tid -> addr stride 37 (cf-free)
#pragma unroll
    for (int j = 0; j < 36; j++) red[e][nl][j] = gder[j];
    __syncthreads();

    // reduce over e: thread owns (nl2,j) pairs; writes into red[0][nl2][j]
    for (int p = tid; p < 32 * 36; p += 256) {
        int nl2 = p / 36, j = p - nl2 * 36;
        float sum = 0.f;
#pragma unroll
        for (int e2 = 0; e2 < 8; e2++) sum += red[e2][nl2][j];
        red[0][nl2][j] = sum;     // only this thread reads/writes (nl2,j)
    }
    __syncthreads();

    // epilogue: 32 threads, one n each
    if (tid < 32) {
        const float* ur = uraw + (size_t)n * (WIN * 5);
        float b127 = cb[127];
        float acc = lb[0];
#pragma unroll
        for (int j = 0; j < 36; j++) {
            float g = b127 + red[0][tid][j];
#pragma unroll
            for (int k = 0; k < 5; k++) g += ur[(j + k) * 5 + k];
            g = (g >= 0.0f) ? g : 0.01f * g;
            acc += g * lw[j];
        }
        outp[n] = acc;
    }
}

// ---------------------------------------------------------------------------
extern "C" void kernel_launch(void* const* d_in, const int* in_sizes, int n_in,
                              void* d_out, int out_size, void* d_ws, size_t ws_size,
                              hipStream_t stream) {
    const float* x  = (const float*)d_in[0];   // [8000,64,64]
    const float* cw = (const float*)d_in[1];   // [128,144,5]
    const float* cb = (const float*)d_in[2];   // [128]
    const float* lw = (const float*)d_in[3];   // [1,36]
    const float* lb = (const float*)d_in[4];   // [1]
    float* outp = (float*)d_out;               // [8000,1]

    float* ws    = (float*)d_ws;
    float* xeT   = ws;                         // 8*59*8000
    float* rankT = ws + XET_SZ;                // 8*40*8000
    float* uraw  = ws + XET_SZ + RNK_SZ;       // 8000*40*5

    k_transpose<<<dim3(32, 59), 256, 0, stream>>>(x, xeT);
    k_rank<<<dim3(WIN, EE), 1024, 0, stream>>>(xeT, rankT);
    k_raw<<<2000, 256, 0, stream>>>(x, cw, uraw);
    k_der_final<<<250, 256, 0, stream>>>(cw, xeT, rankT, uraw, cb, lw, lb, outp);
}

// Round 5
// 244.747 us; speedup vs baseline: 1.3522x; 1.0336x over previous
//
#include <hip/hip_runtime.h>
#include <math.h>

// Problem constants
#define NS    8000      // N samples
#define TT    64        // T
#define FF    64        // F
#define EE    8         // E
#define WIN   40        // WINDOW
#define TR    59        // rows of xe kept: t = 5..63
#define NBINS 8192

// ws layout (floats):
//   xeT  [8][59][8000]  = 3,776,000
//   rankT[8][40][8000]  = 2,560,000
//   uraw [8000][40][5]  = 1,600,000
#define XET_SZ  (8*59*8000)
#define RNK_SZ  (8*40*8000)

// ---------------------------------------------------------------------------
// K0: fused transpose + raw-channel conv fold.
// Thread (n, r): r = t-5 in 0..58. Always: transpose x[:, 5+r, 0:8] -> xeT.
// For r>=19 (t=24..63, w=r-19): load full 64-feature row, fold into
// u[n][w][k] = dot(row, W127[:,k]). W offsets are lane-uniform -> scalar
// loads; no LDS, no shuffles.
// ---------------------------------------------------------------------------
__global__ __launch_bounds__(256) void k0(const float* __restrict__ x,
                                          const float* __restrict__ cw,
                                          float* __restrict__ xeT,
                                          float* __restrict__ uraw) {
    int n = blockIdx.x * 256 + threadIdx.x;
    int r = blockIdx.y;              // 0..58
    if (n >= NS) return;
    const float* row = x + (size_t)n * (TT * FF) + (5 + r) * FF;
    float4 a = *(const float4*)(row);
    float4 b = *(const float4*)(row + 4);
    xeT[(0 * TR + r) * NS + n] = a.x;
    xeT[(1 * TR + r) * NS + n] = a.y;
    xeT[(2 * TR + r) * NS + n] = a.z;
    xeT[(3 * TR + r) * NS + n] = a.w;
    xeT[(4 * TR + r) * NS + n] = b.x;
    xeT[(5 * TR + r) * NS + n] = b.y;
    xeT[(6 * TR + r) * NS + n] = b.z;
    xeT[(7 * TR + r) * NS + n] = b.w;

    if (r >= 19) {                   // t = 24+w, w = r-19
        const int w = r - 19;
        const float* W = cw + 127 * 144 * 5;
        float4 v[16];
        v[0] = a; v[1] = b;
#pragma unroll
        for (int q = 2; q < 16; q++) v[q] = *(const float4*)(row + 4 * q);
        float acc0 = 0.f, acc1 = 0.f, acc2 = 0.f, acc3 = 0.f, acc4 = 0.f;
#pragma unroll
        for (int q = 0; q < 16; q++) {
            const float* Wq = W + (4 * q) * 5;   // uniform -> s_load
            acc0 += v[q].x * Wq[0]  + v[q].y * Wq[5]  + v[q].z * Wq[10] + v[q].w * Wq[15];
            acc1 += v[q].x * Wq[1]  + v[q].y * Wq[6]  + v[q].z * Wq[11] + v[q].w * Wq[16];
            acc2 += v[q].x * Wq[2]  + v[q].y * Wq[7]  + v[q].z * Wq[12] + v[q].w * Wq[17];
            acc3 += v[q].x * Wq[3]  + v[q].y * Wq[8]  + v[q].z * Wq[13] + v[q].w * Wq[18];
            acc4 += v[q].x * Wq[4]  + v[q].y * Wq[9]  + v[q].z * Wq[14] + v[q].w * Wq[19];
        }
        float* o = uraw + ((size_t)n * WIN + w) * 5;
        o[0] = acc0; o[1] = acc1; o[2] = acc2; o[3] = acc3; o[4] = acc4;
    }
}

// ---------------------------------------------------------------------------
// KR v3: exact cross-batch descending rank via 64-bit sortable keys.
// key = (~mono_asc(v) << 13) | idx  -> rank = #{key_j < key_i} exactly
// matches (value desc, index asc) stable argsort. 8192 value-linear bins
// over [-4,4] (avg bucket ~2.2). Single sk[] u64 array; bend[b]=basev[b-1].
// LDS = 32K hist + 32K basev + 64K keys = 129.6 KB -> 1 block/CU, 16 waves.
// ---------------------------------------------------------------------------
__device__ __forceinline__ int binOf(float v) {
    int b = (int)((v + 4.0f) * 1024.0f);   // monotone; clamped
    b = b < 0 ? 0 : b;
    return b > (NBINS - 1) ? (NBINS - 1) : b;
}

__device__ __forceinline__ unsigned long long keyOf(float v, unsigned idx) {
    unsigned s = __float_as_uint(v);
    unsigned m = (s & 0x80000000u) ? (~s) : (s | 0x80000000u); // ascending mono
    unsigned md = ~m;                                          // descending
    return ((unsigned long long)md << 13) | idx;
}

__global__ __launch_bounds__(1024) void k_rank(const float* __restrict__ xeT,
                                               float* __restrict__ rankT) {
    const int w = blockIdx.x;   // 0..39
    const int e = blockIdx.y;   // 0..7
    __shared__ unsigned hist[NBINS];             // scatter cursor after scan
    __shared__ unsigned basev[NBINS];            // # elems in greater buckets
    __shared__ unsigned long long sk[NS];        // bucket-grouped keys
    __shared__ unsigned wsum[16];

    const int tid  = threadIdx.x;
    const int lane = tid & 63;
    const int wid  = tid >> 6;
    const float* col = xeT + ((size_t)e * TR + (19 + w)) * NS;   // t = 24+w

    float val[8];
#pragma unroll
    for (int i = 0; i < 8; i++) {
        int idx = tid + i * 1024;
        val[i] = (idx < NS) ? col[idx] : 0.0f;
    }
#pragma unroll
    for (int j = 0; j < 8; j++) hist[tid + j * 1024] = 0;
    __syncthreads();

#pragma unroll
    for (int i = 0; i < 8; i++) {
        int idx = tid + i * 1024;
        if (idx < NS) atomicAdd(&hist[binOf(val[i])], 1u);
    }
    __syncthreads();

    // suffix offsets: 8 bins/thread; wave scan + cross-wave offsets
    unsigned h[8];
#pragma unroll
    for (int j = 0; j < 8; j++) h[j] = hist[8 * tid + j];
    unsigned cs = 0;
#pragma unroll
    for (int j = 0; j < 8; j++) cs += h[j];
    unsigned sc = cs;
#pragma unroll
    for (int d = 1; d < 64; d <<= 1) {
        unsigned t2 = __shfl_up(sc, d);
        if (lane >= d) sc += t2;
    }
    if (lane == 63) wsum[wid] = sc;
    __syncthreads();
    unsigned woff = 0;
    for (int i = 0; i < wid; i++) woff += wsum[i];
    unsigned bsum = woff + (sc - cs);   // # elements in bins < 8*tid
#pragma unroll
    for (int j = 0; j < 8; j++) {
        int b = 8 * tid + j;
        unsigned bv = NS - bsum - h[j];
        basev[b] = bv;
        hist[b]  = bv;                  // scatter cursor
        bsum += h[j];
    }
    __syncthreads();

    // scatter keys into bucket-grouped order (order within bucket irrelevant)
#pragma unroll
    for (int i = 0; i < 8; i++) {
        int idx = tid + i * 1024;
        if (idx < NS) {
            int b = binOf(val[i]);
            unsigned p = atomicAdd(&hist[b], 1u);
            sk[p] = keyOf(val[i], (unsigned)idx);
        }
    }
    __syncthreads();

    // exact rank: greater-bucket count + within-bucket key comparisons.
    // Consecutive p -> lanes in adjacent buckets -> short wave-max scans.
    float* outp = rankT + ((size_t)e * WIN + w) * NS;
#pragma unroll 1
    for (int i = 0; i < 8; i++) {
        int p = tid + i * 1024;
        if (p < NS) {
            unsigned long long k64 = sk[p];
            // recover value bit-exactly from key to re-derive the bin
            unsigned md = (unsigned)(k64 >> 13);
            unsigned m  = ~md;
            unsigned s  = (m & 0x80000000u) ? (m ^ 0x80000000u) : (~m);
            float v = __uint_as_float(s);
            int b = binOf(v);
            unsigned lo = basev[b];
            unsigned hi = (b == 0) ? NS : basev[b - 1];
            unsigned c = 0;
            for (unsigned q = lo; q < hi; q++) c += (sk[q] < k64);
            outp[k64 & 8191u] = (float)(basev[b] + c) * (1.0f / 8000.0f);
        }
    }
}

// ---------------------------------------------------------------------------
// KDF: fused derived-stats + conv-fold + epilogue. Thread = (n,e); 20-reg
// sliding ring over 59 xeT rows (xeT read exactly once). Weights preloaded
// to registers. LDS e-reduction ([8][32][37], conflict-free); 32 threads do
// the leaky+dot epilogue per block.
// ---------------------------------------------------------------------------
__global__ __launch_bounds__(256) void k_der_final(const float* __restrict__ cw,
                                                   const float* __restrict__ xeT,
                                                   const float* __restrict__ rankT,
                                                   const float* __restrict__ uraw,
                                                   const float* __restrict__ cb,
                                                   const float* __restrict__ lw,
                                                   const float* __restrict__ lb,
                                                   float* __restrict__ outp) {
    __shared__ float red[8][32][37];
    const int tid = threadIdx.x;
    const int e   = tid >> 5;          // 0..7
    const int nl  = tid & 31;          // 0..31
    const int n0  = blockIdx.x * 32;   // 250 blocks * 32 = 8000
    const int n   = n0 + nl;
    const float* W = cw + 127 * 144 * 5;

    // preload this e's 45 weights (rank folds two channels)
    float wm5[5], wsd5[5], wrk[5], wmx5[5], wmn5[5], wm20[5], wsd20[5], wmx20[5], wmn20[5];
#pragma unroll
    for (int k = 0; k < 5; k++) {
        wm5[k]   = W[(64  + e) * 5 + k];
        wsd5[k]  = W[(72  + e) * 5 + k];
        wrk[k]   = W[(80  + e) * 5 + k] + W[(120 + e) * 5 + k];
        wmx5[k]  = W[(88  + e) * 5 + k];
        wmn5[k]  = W[(96  + e) * 5 + k];
        wm20[k]  = W[(104 + e) * 5 + k];
        wsd20[k] = W[(112 + e) * 5 + k];
        wmx20[k] = W[(128 + e) * 5 + k];
        wmn20[k] = W[(136 + e) * 5 + k];
    }

    float gder[36];
#pragma unroll
    for (int j = 0; j < 36; j++) gder[j] = 0.0f;

    const float* col = xeT + (size_t)e * TR * NS + n;
    const float* rkp = rankT + (size_t)e * WIN * NS + n;

    float ring[20];
#pragma unroll
    for (int r = 0; r < 19; r++) ring[r] = col[(size_t)r * NS];

#pragma unroll
    for (int w = 0; w < WIN; w++) {
        ring[(w + 19) % 20] = col[(size_t)(w + 19) * NS];
        // month window = rows w..w+19 (all 20 ring slots; order irrelevant)
        float s20 = 0.f, mn20 = ring[0], mx20 = ring[0];
#pragma unroll
        for (int i = 0; i < 20; i++) {
            float v = ring[i];
            s20 += v; mn20 = fminf(mn20, v); mx20 = fmaxf(mx20, v);
        }
        float m20 = s20 * (1.0f / 20.0f);
        float d20 = 0.f;
#pragma unroll
        for (int i = 0; i < 20; i++) { float t = ring[i] - m20; d20 += t * t; }
        float sd20 = sqrtf(d20 * (1.0f / 19.0f));

        // week window = rows w+15..w+19
        float s5 = 0.f, mn5 = ring[(w + 15) % 20], mx5 = mn5;
#pragma unroll
        for (int i = 15; i < 20; i++) {
            float v = ring[(w + i) % 20];
            s5 += v; mn5 = fminf(mn5, v); mx5 = fmaxf(mx5, v);
        }
        float m5 = s5 * 0.2f;
        float d5 = 0.f;
#pragma unroll
        for (int i = 15; i < 20; i++) {
            float t = ring[(w + i) % 20] - m5; d5 += t * t;
        }
        float sd5 = sqrtf(d5 * 0.25f);

        float rk = rkp[(size_t)w * NS];

#pragma unroll
        for (int k = 0; k < 5; k++) {
            int j = w - k;
            if (j >= 0 && j < 36) {
                float uk;
                uk  = m5   * wm5[k];
                uk += sd5  * wsd5[k];
                uk += rk   * wrk[k];
                uk += mx5  * wmx5[k];
                uk += mn5  * wmn5[k];
                uk += m20  * wm20[k];
                uk += sd20 * wsd20[k];
                uk += mx20 * wmx20[k];
                uk += mn20 * wmn20[k];
                gder[j] += uk;
            }
        }
    }

    // stage partials: red[e][nl][j]; consecutive tid -> addr stride 37 (cf-free)
#pragma unroll
    for (int j = 0; j < 36; j++) red[e][nl][j] = gder[j];
    __syncthreads();

    // reduce over e: thread owns (nl2,j) pairs; writes into red[0][nl2][j]
    for (int p = tid; p < 32 * 36; p += 256) {
        int nl2 = p / 36, j = p - nl2 * 36;
        float sum = 0.f;
#pragma unroll
        for (int e2 = 0; e2 < 8; e2++) sum += red[e2][nl2][j];
        red[0][nl2][j] = sum;     // only this thread reads/writes (nl2,j)
    }
    __syncthreads();

    // epilogue: 32 threads, one n each
    if (tid < 32) {
        const float* ur = uraw + (size_t)n * (WIN * 5);
        float b127 = cb[127];
        float acc = lb[0];
#pragma unroll
        for (int j = 0; j < 36; j++) {
            float g = b127 + red[0][tid][j];
#pragma unroll
            for (int k = 0; k < 5; k++) g += ur[(j + k) * 5 + k];
            g = (g >= 0.0f) ? g : 0.01f * g;
            acc += g * lw[j];
        }
        outp[n] = acc;
    }
}

// ---------------------------------------------------------------------------
extern "C" void kernel_launch(void* const* d_in, const int* in_sizes, int n_in,
                              void* d_out, int out_size, void* d_ws, size_t ws_size,
                              hipStream_t stream) {
    const float* x  = (const float*)d_in[0];   // [8000,64,64]
    const float* cw = (const float*)d_in[1];   // [128,144,5]
    const float* cb = (const float*)d_in[2];   // [128]
    const float* lw = (const float*)d_in[3];   // [1,36]
    const float* lb = (const float*)d_in[4];   // [1]
    float* outp = (float*)d_out;               // [8000,1]

    float* ws    = (float*)d_ws;
    float* xeT   = ws;                         // 8*59*8000
    float* rankT = ws + XET_SZ;                // 8*40*8000
    float* uraw  = ws + XET_SZ + RNK_SZ;       // 8000*40*5

    k0<<<dim3(32, 59), 256, 0, stream>>>(x, cw, xeT, uraw);
    k_rank<<<dim3(WIN, EE), 1024, 0, stream>>>(xeT, rankT);
    k_der_final<<<250, 256, 0, stream>>>(cw, xeT, rankT, uraw, cb, lw, lb, outp);
}